// Round 1
// baseline (105.189 us; speedup 1.0000x reference)
//
#include <hip/hip_runtime.h>

// DenseGATConv collapses algebraically:
//   x is replaced by ones -> xh[b,n,h,c] = colsum[h,c] = sum_f W_lin[f, h*C+c]
//   -> attention logits constant over j before the diff bias; softmax rows sum to 1
//   -> out[b,n,c] = (1/H) * sum_h colsum[h,c]   (broadcast over B*N)
// Only W_lin (d_in[3], 128x256 fp32) matters.

#define GAT_F   128
#define GAT_H   4
#define GAT_C   64
#define GAT_HC  256   // H*C
#define OUT_F4  131072  // 8*1024*64 floats / 4

// One block, 256 threads: column sums of W_lin, then fold the 4 heads.
__global__ void gat_colsum_kernel(const float* __restrict__ W, float* __restrict__ r) {
    __shared__ float cs[GAT_HC];
    const int t = threadIdx.x;  // 0..255 -> column hc
    float s = 0.0f;
    #pragma unroll 8
    for (int f = 0; f < GAT_F; ++f) {
        s += W[f * GAT_HC + t];   // coalesced: consecutive t -> consecutive addr
    }
    cs[t] = s;
    __syncthreads();
    if (t < GAT_C) {
        r[t] = 0.25f * (cs[t] + cs[t + 64] + cs[t + 128] + cs[t + 192]);
    }
}

// Broadcast the 64-float vector across B*N rows. Pattern repeats every 16 float4s.
__global__ void gat_broadcast_kernel(const float4* __restrict__ r4, float4* __restrict__ out) {
    const int idx = blockIdx.x * blockDim.x + threadIdx.x;  // float4 index
    out[idx] = r4[idx & 15];
}

extern "C" void kernel_launch(void* const* d_in, const int* in_sizes, int n_in,
                              void* d_out, int out_size, void* d_ws, size_t ws_size,
                              hipStream_t stream) {
    const float* W_lin = (const float*)d_in[3];   // [F, H*C] = [128, 256]
    float* r = (float*)d_ws;                      // 64 floats scratch
    float* out = (float*)d_out;                   // [B, N, C] = 524288 floats

    gat_colsum_kernel<<<1, 256, 0, stream>>>(W_lin, r);

    // 524288 floats = 131072 float4s; 512 blocks x 256 threads
    gat_broadcast_kernel<<<OUT_F4 / 256, 256, 0, stream>>>(
        (const float4*)r, (float4*)out);
}

// Round 2
// 102.310 us; speedup vs baseline: 1.0281x; 1.0281x over previous
//
#include <hip/hip_runtime.h>

// DenseGATConv collapses algebraically:
//   x is replaced by ones -> xh[b,n,h,c] = colsum[h,c] = sum_f W_lin[f, h*C+c]
//   -> attention logits constant over j before the diff bias (softmax shift-invariant,
//      every row has a self-loop) -> softmax rows sum to exactly 1
//   -> out[b,n,c] = (1/H) * sum_h colsum[h,c]   (broadcast over B*N)
// Only W_lin (d_in[3], [128,256] fp32) matters.
//
// Fused single kernel: every block recomputes the 64-float fold from W_lin
// (128 KB, L2-resident after first touch), then writes its output slice.
// No d_ws use, no inter-kernel dependency, one launch.

#define GAT_F   128
#define GAT_HC  256     // H*C
#define OUT_F4  131072  // 8*1024*64 floats / 4

__global__ __launch_bounds__(256) void gat_fused_kernel(
        const float* __restrict__ W, float4* __restrict__ out) {
    __shared__ float cs[GAT_HC];
    __shared__ float4 r4[16];    // the 64-float result vector

    const int t = threadIdx.x;   // 0..255 -> column hc of W_lin
    float s = 0.0f;
    #pragma unroll 16
    for (int f = 0; f < GAT_F; ++f) {
        s += W[f * GAT_HC + t];  // coalesced 1 KB/wave loads, L2-hit after block 0
    }
    cs[t] = s;
    __syncthreads();
    if (t < 64) {
        ((float*)r4)[t] = 0.25f * (cs[t] + cs[t + 64] + cs[t + 128] + cs[t + 192]);
    }
    __syncthreads();

    // One float4 per thread; pattern repeats every 16 float4s (64 floats).
    const int idx = blockIdx.x * 256 + t;
    out[idx] = r4[idx & 15];
}

extern "C" void kernel_launch(void* const* d_in, const int* in_sizes, int n_in,
                              void* d_out, int out_size, void* d_ws, size_t ws_size,
                              hipStream_t stream) {
    const float* W_lin = (const float*)d_in[3];  // [F, H*C] = [128, 256] fp32
    (void)d_ws; (void)ws_size;

    gat_fused_kernel<<<OUT_F4 / 256, 256, 0, stream>>>(W_lin, (float4*)d_out);
}